// Round 16
// baseline (141.559 us; speedup 1.0000x reference)
//
#include <hip/hip_runtime.h>
#include <hip/hip_bf16.h>
#include <math.h>

#define HID 64
#define TSEQ 96
#define NOUT 96
#define NIN 5
#define FLATN (TSEQ * NOUT)   // 9216

#define LOG2E 1.4426950408889634f

typedef float f32x4 __attribute__((ext_vector_type(4)));

__device__ __forceinline__ float fast_sigmoid(float x) {
    return __builtin_amdgcn_rcpf(1.0f + __builtin_amdgcn_exp2f(-LOG2E * x));
}

__device__ __forceinline__ float fast_tanh(float x) {
    const float ax = fabsf(x);
    const float e = __builtin_amdgcn_exp2f(-2.0f * LOG2E * ax);
    const float t = (1.0f - e) * __builtin_amdgcn_rcpf(1.0f + e);
    return copysignf(t, x);
}

__device__ __forceinline__ float bcast(float v, int l) {
    return __uint_as_float(__builtin_amdgcn_readlane(__float_as_uint(v), l));
}

// ---- single-wave LSTM: lane owns unit `lane`, ALL 4 gate rows in-lane ----
// 64 f32x4 weight quads: 60 pinned to AGPRs ("a"), 4 to VGPRs (hedge).
// Per step: 64 shared readlane broadcasts + 256 FMA + 5 activations.
// ZERO LDS, ZERO barriers inside the 96-step loop (r15 post-mortem: the
// barrier-to-barrier serial path was the invariant ~1300ns/step cost that
// no weight-tier change could touch).

#define MVQ(Q, WI, WF, WG, WO, AI, AF, AG, AO)                                \
    {                                                                         \
        const float hb0 = bcast(h, 4 * Q + 0);                                \
        const float hb1 = bcast(h, 4 * Q + 1);                                \
        const float hb2 = bcast(h, 4 * Q + 2);                                \
        const float hb3 = bcast(h, 4 * Q + 3);                                \
        AI = fmaf(WI.x, hb0, AI); AI = fmaf(WI.y, hb1, AI);                   \
        AI = fmaf(WI.z, hb2, AI); AI = fmaf(WI.w, hb3, AI);                   \
        AF = fmaf(WF.x, hb0, AF); AF = fmaf(WF.y, hb1, AF);                   \
        AF = fmaf(WF.z, hb2, AF); AF = fmaf(WF.w, hb3, AF);                   \
        AG = fmaf(WG.x, hb0, AG); AG = fmaf(WG.y, hb1, AG);                   \
        AG = fmaf(WG.z, hb2, AG); AG = fmaf(WG.w, hb3, AG);                   \
        AO = fmaf(WO.x, hb0, AO); AO = fmaf(WO.y, hb1, AO);                   \
        AO = fmaf(WO.z, hb2, AO); AO = fmaf(WO.w, hb3, AO);                   \
    }

__global__ __launch_bounds__(256, 1)
__attribute__((amdgpu_waves_per_eu(1, 1)))
void lstm_fused(
    const float* __restrict__ x,     // (96, 5)
    const float* __restrict__ h0,    // (64)
    const float* __restrict__ c0,    // (64)
    const float* __restrict__ Wih,   // (256, 5)
    const float* __restrict__ Whh,   // (256, 64)
    const float* __restrict__ bih,   // (256)
    const float* __restrict__ bhh,   // (256)
    const float* __restrict__ W1,    // (96, 64)
    const float* __restrict__ b1,    // (96)
    float* __restrict__ flat_out)    // (9216) workspace
{
    __shared__ float x_s[TSEQ * NIN];
    __shared__ float hseq[TSEQ][HID];

    const int tid  = threadIdx.x;
    const int lane = tid & 63;
    const int wv   = tid >> 6;

    for (int i = tid; i < TSEQ * NIN; i += 256) x_s[i] = x[i];
    __syncthreads();

    if (wv == 0) {
        // ---- all 4 gate rows for unit `lane` -> 64 quads, mostly AGPRs ----
        const f32x4* WrI = reinterpret_cast<const f32x4*>(Whh + (0 * HID + lane) * HID);
        const f32x4* WrF = reinterpret_cast<const f32x4*>(Whh + (1 * HID + lane) * HID);
        const f32x4* WrG = reinterpret_cast<const f32x4*>(Whh + (2 * HID + lane) * HID);
        const f32x4* WrO = reinterpret_cast<const f32x4*>(Whh + (3 * HID + lane) * HID);
        f32x4 wI0=WrI[0], wI1=WrI[1], wI2=WrI[2],  wI3=WrI[3],
              wI4=WrI[4], wI5=WrI[5], wI6=WrI[6],  wI7=WrI[7],
              wI8=WrI[8], wI9=WrI[9], wI10=WrI[10],wI11=WrI[11],
              wI12=WrI[12],wI13=WrI[13],wI14=WrI[14],wI15=WrI[15];
        f32x4 wF0=WrF[0], wF1=WrF[1], wF2=WrF[2],  wF3=WrF[3],
              wF4=WrF[4], wF5=WrF[5], wF6=WrF[6],  wF7=WrF[7],
              wF8=WrF[8], wF9=WrF[9], wF10=WrF[10],wF11=WrF[11],
              wF12=WrF[12],wF13=WrF[13],wF14=WrF[14],wF15=WrF[15];
        f32x4 wG0=WrG[0], wG1=WrG[1], wG2=WrG[2],  wG3=WrG[3],
              wG4=WrG[4], wG5=WrG[5], wG6=WrG[6],  wG7=WrG[7],
              wG8=WrG[8], wG9=WrG[9], wG10=WrG[10],wG11=WrG[11],
              wG12=WrG[12],wG13=WrG[13],wG14=WrG[14],wG15=WrG[15];
        f32x4 wO0=WrO[0], wO1=WrO[1], wO2=WrO[2],  wO3=WrO[3],
              wO4=WrO[4], wO5=WrO[5], wO6=WrO[6],  wO7=WrO[7],
              wO8=WrO[8], wO9=WrO[9], wO10=WrO[10],wO11=WrO[11],
              wO12=WrO[12],wO13=WrO[13],wO14=WrO[14],wO15=WrO[15];

        asm volatile("" : "+a"(wI0), "+a"(wI1), "+a"(wI2),  "+a"(wI3),
                          "+a"(wI4), "+a"(wI5), "+a"(wI6),  "+a"(wI7));
        asm volatile("" : "+a"(wI8), "+a"(wI9), "+a"(wI10), "+a"(wI11),
                          "+a"(wI12),"+a"(wI13),"+a"(wI14), "+a"(wI15));
        asm volatile("" : "+a"(wF0), "+a"(wF1), "+a"(wF2),  "+a"(wF3),
                          "+a"(wF4), "+a"(wF5), "+a"(wF6),  "+a"(wF7));
        asm volatile("" : "+a"(wF8), "+a"(wF9), "+a"(wF10), "+a"(wF11),
                          "+a"(wF12),"+a"(wF13),"+a"(wF14), "+a"(wF15));
        asm volatile("" : "+a"(wG0), "+a"(wG1), "+a"(wG2),  "+a"(wG3),
                          "+a"(wG4), "+a"(wG5), "+a"(wG6),  "+a"(wG7));
        asm volatile("" : "+a"(wG8), "+a"(wG9), "+a"(wG10), "+a"(wG11),
                          "+a"(wG12),"+a"(wG13),"+a"(wG14), "+a"(wG15));
        asm volatile("" : "+a"(wO0), "+a"(wO1), "+a"(wO2),  "+a"(wO3),
                          "+a"(wO4), "+a"(wO5), "+a"(wO6),  "+a"(wO7));
        asm volatile("" : "+a"(wO8), "+a"(wO9), "+a"(wO10), "+a"(wO11),
                          "+v"(wO12),"+v"(wO13),"+v"(wO14), "+v"(wO15));

        const float wiI0 = Wih[(0*HID+lane)*NIN+0], wiI1 = Wih[(0*HID+lane)*NIN+1],
                    wiI2 = Wih[(0*HID+lane)*NIN+2], wiI3 = Wih[(0*HID+lane)*NIN+3],
                    wiI4 = Wih[(0*HID+lane)*NIN+4];
        const float wiF0 = Wih[(1*HID+lane)*NIN+0], wiF1 = Wih[(1*HID+lane)*NIN+1],
                    wiF2 = Wih[(1*HID+lane)*NIN+2], wiF3 = Wih[(1*HID+lane)*NIN+3],
                    wiF4 = Wih[(1*HID+lane)*NIN+4];
        const float wiG0 = Wih[(2*HID+lane)*NIN+0], wiG1 = Wih[(2*HID+lane)*NIN+1],
                    wiG2 = Wih[(2*HID+lane)*NIN+2], wiG3 = Wih[(2*HID+lane)*NIN+3],
                    wiG4 = Wih[(2*HID+lane)*NIN+4];
        const float wiO0 = Wih[(3*HID+lane)*NIN+0], wiO1 = Wih[(3*HID+lane)*NIN+1],
                    wiO2 = Wih[(3*HID+lane)*NIN+2], wiO3 = Wih[(3*HID+lane)*NIN+3],
                    wiO4 = Wih[(3*HID+lane)*NIN+4];
        const float bI = bih[0*HID+lane] + bhh[0*HID+lane];
        const float bF = bih[1*HID+lane] + bhh[1*HID+lane];
        const float bG = bih[2*HID+lane] + bhh[2*HID+lane];
        const float bO = bih[3*HID+lane] + bhh[3*HID+lane];

        float h = h0[lane];
        float c = c0[lane];

        float nx0 = x_s[0], nx1 = x_s[1], nx2 = x_s[2], nx3 = x_s[3], nx4 = x_s[4];

#pragma unroll 1
        for (int t = 0; t < TSEQ; ++t) {
            const float xt0 = nx0, xt1 = nx1, xt2 = nx2, xt3 = nx3, xt4 = nx4;
            const int tn = (t + 1 < TSEQ) ? (t + 1) : t;
            nx0 = x_s[tn * NIN + 0];
            nx1 = x_s[tn * NIN + 1];
            nx2 = x_s[tn * NIN + 2];
            nx3 = x_s[tn * NIN + 3];
            nx4 = x_s[tn * NIN + 4];

            // x-projection, 2 accumulators per gate
            float aI0 = fmaf(wiI0, xt0, bI), aI1 = wiI1 * xt1;
            float aF0 = fmaf(wiF0, xt0, bF), aF1 = wiF1 * xt1;
            float aG0 = fmaf(wiG0, xt0, bG), aG1 = wiG1 * xt1;
            float aO0 = fmaf(wiO0, xt0, bO), aO1 = wiO1 * xt1;
            aI0 = fmaf(wiI2, xt2, aI0); aI1 = fmaf(wiI3, xt3, aI1);
            aF0 = fmaf(wiF2, xt2, aF0); aF1 = fmaf(wiF3, xt3, aF1);
            aG0 = fmaf(wiG2, xt2, aG0); aG1 = fmaf(wiG3, xt3, aG1);
            aO0 = fmaf(wiO2, xt2, aO0); aO1 = fmaf(wiO3, xt3, aO1);
            aI0 = fmaf(wiI4, xt4, aI0);
            aF0 = fmaf(wiF4, xt4, aF0);
            aG0 = fmaf(wiG4, xt4, aG0);
            aO0 = fmaf(wiO4, xt4, aO0);

            // recurrent matvec: 64 shared broadcasts, 256 FMA, all in-lane
            MVQ(0,  wI0,  wF0,  wG0,  wO0,  aI0, aF0, aG0, aO0)
            MVQ(1,  wI1,  wF1,  wG1,  wO1,  aI1, aF1, aG1, aO1)
            MVQ(2,  wI2,  wF2,  wG2,  wO2,  aI0, aF0, aG0, aO0)
            MVQ(3,  wI3,  wF3,  wG3,  wO3,  aI1, aF1, aG1, aO1)
            MVQ(4,  wI4,  wF4,  wG4,  wO4,  aI0, aF0, aG0, aO0)
            MVQ(5,  wI5,  wF5,  wG5,  wO5,  aI1, aF1, aG1, aO1)
            MVQ(6,  wI6,  wF6,  wG6,  wO6,  aI0, aF0, aG0, aO0)
            MVQ(7,  wI7,  wF7,  wG7,  wO7,  aI1, aF1, aG1, aO1)
            MVQ(8,  wI8,  wF8,  wG8,  wO8,  aI0, aF0, aG0, aO0)
            MVQ(9,  wI9,  wF9,  wG9,  wO9,  aI1, aF1, aG1, aO1)
            MVQ(10, wI10, wF10, wG10, wO10, aI0, aF0, aG0, aO0)
            MVQ(11, wI11, wF11, wG11, wO11, aI1, aF1, aG1, aO1)
            MVQ(12, wI12, wF12, wG12, wO12, aI0, aF0, aG0, aO0)
            MVQ(13, wI13, wF13, wG13, wO13, aI1, aF1, aG1, aO1)
            MVQ(14, wI14, wF14, wG14, wO14, aI0, aF0, aG0, aO0)
            MVQ(15, wI15, wF15, wG15, wO15, aI1, aF1, aG1, aO1)

            const float ig = fast_sigmoid(aI0 + aI1);
            const float fg = fast_sigmoid(aF0 + aF1);
            const float gg = fast_tanh(aG0 + aG1);
            const float og = fast_sigmoid(aO0 + aO1);
            c = fmaf(fg, c, ig * gg);
            h = og * fast_tanh(c);
            hseq[t][lane] = h;
        }
    }

    __syncthreads();

    // ---- linear1: flat[t*96 + k] = b1[k] + W1[k,:] . hseq[t,:] ----
    {
        const float4* __restrict__ W1v = reinterpret_cast<const float4*>(W1);
#pragma unroll 1
        for (int i = 0; i < FLATN / 256; ++i) {      // 36 iterations
            const int idx = tid + i * 256;
            const int t = idx / NOUT;
            const int k = idx - t * NOUT;
            const float4* hv = reinterpret_cast<const float4*>(&hseq[t][0]);
            float s0 = 0.f, s1 = 0.f, s2 = 0.f, s3 = 0.f;
#pragma unroll
            for (int j4 = 0; j4 < 16; ++j4) {
                const float4 a = W1v[k * 16 + j4];
                const float4 hb = hv[j4];
                s0 = fmaf(a.x, hb.x, s0);
                s1 = fmaf(a.y, hb.y, s1);
                s2 = fmaf(a.z, hb.z, s2);
                s3 = fmaf(a.w, hb.w, s3);
            }
            flat_out[idx] = b1[k] + ((s0 + s1) + (s2 + s3));
        }
    }
}

// Kernel 2: out[o] = b2[o] + W2[o,:] . flat   (96 blocks, one output each)
__global__ __launch_bounds__(256) void gemv_final_kernel(
    const float* __restrict__ W2,    // (96, 9216)
    const float* __restrict__ b2,    // (96)
    const float* __restrict__ flat,  // (9216)
    float* __restrict__ out)         // (96)
{
    const int o = blockIdx.x;
    const int tid = threadIdx.x;
    const float* __restrict__ row = &W2[o * FLATN];

    float s = 0.f;
#pragma unroll 4
    for (int j = tid; j < FLATN; j += 256) {
        s += row[j] * flat[j];
    }

#pragma unroll
    for (int off = 32; off > 0; off >>= 1) s += __shfl_down(s, off, 64);

    __shared__ float partial[4];
    if ((tid & 63) == 0) partial[tid >> 6] = s;
    __syncthreads();
    if (tid == 0) {
        out[o] = b2[o] + ((partial[0] + partial[1]) + (partial[2] + partial[3]));
    }
}

extern "C" void kernel_launch(void* const* d_in, const int* in_sizes, int n_in,
                              void* d_out, int out_size, void* d_ws, size_t ws_size,
                              hipStream_t stream) {
    const float* x   = (const float*)d_in[0];
    const float* h0  = (const float*)d_in[1];
    const float* c0  = (const float*)d_in[2];
    const float* Wih = (const float*)d_in[3];
    const float* Whh = (const float*)d_in[4];
    const float* bih = (const float*)d_in[5];
    const float* bhh = (const float*)d_in[6];
    const float* W1  = (const float*)d_in[7];
    const float* b1  = (const float*)d_in[8];
    const float* W2  = (const float*)d_in[9];
    const float* b2  = (const float*)d_in[10];

    float* out  = (float*)d_out;
    float* flat = (float*)d_ws;   // 9216 floats

    lstm_fused<<<1, 256, 0, stream>>>(x, h0, c0, Wih, Whh, bih, bhh, W1, b1, flat);
    gemv_final_kernel<<<NOUT, 256, 0, stream>>>(W2, b2, flat, out);
}